// Round 7
// baseline (71.114 us; speedup 1.0000x reference)
//
#include <hip/hip_runtime.h>
#include <hip/hip_bf16.h>

// InfoNCE loss, B=8, N=2048, D=256, T=0.1 — mask-compacted, XCD-local,
// register-resident B with a sched_barrier-pinned 2-deep load pipeline.
// ws layout (~9.6 MB):
//   [0]       float gsum[16] (0: loss sum, 1: count)
//   [64]      int   done
//   [128]     int   mcnt[B]
//   [192]     int   idx[B][2048]      compacted -> original index
//   [65728]   int   gc[B][2048]       compacted groups (pad = 0x10000)
//   [131264]  ushort zc[B][2048][256] compacted bf16-normalized rows
//   [8519872] float pd[NCH][B][2048]  per-chunk denom partials
//   [9044160] float pn[NCH][B][2048]  per-chunk numer partials

#define B_ 8
#define N_ 2048
#define D_ 256
#define NCH 4     // column-tile chunks (tile t -> chunk t%NCH)
#define BROWS 64  // rows per block = 4 waves x 16 rows
#define NEGB -16384.0f

typedef __attribute__((ext_vector_type(8))) short bf16x8;
typedef __attribute__((ext_vector_type(4))) float f32x4;

#define SB() __builtin_amdgcn_sched_barrier(0)

// One block per batch: detect mask dtype, prefix-scan mask, emit compacted
// index list + compacted groups (+sentinel pad), per-batch count. Block 0
// also zeroes the global accumulators.
__global__ void scan_kernel(const void* __restrict__ maskRaw, const int* __restrict__ groups,
                            int* __restrict__ idx, int* __restrict__ gc,
                            int* __restrict__ mcnt, float* gsum, int* done) {
  const int b = blockIdx.x, tid = threadIdx.x;
  __shared__ int cnt_s;
  __shared__ int warpOff[4];
  if (tid == 0) cnt_s = 0;
  __syncthreads();
  // dtype detect over first 16KB (in-bounds for both bool and int32)
  const int4* p4 = (const int4*)maskRaw;
  int c = 0;
  for (int i = tid; i < 1024; i += 256) {
    const int4 v = p4[i];
    c += ((v.x & 0xFFFFFF00) != 0) + ((v.y & 0xFFFFFF00) != 0) +
         ((v.z & 0xFFFFFF00) != 0) + ((v.w & 0xFFFFFF00) != 0);
  }
  atomicAdd(&cnt_s, c);
  __syncthreads();
  const bool isInt = (cnt_s == 0);  // int32 0/1 values: upper bytes all zero

  unsigned int bits = 0;
  if (isInt) {
    const int* ip = (const int*)maskRaw + b * N_ + tid * 8;
#pragma unroll
    for (int e = 0; e < 8; e++) bits |= (unsigned)(ip[e] != 0) << e;
  } else {
    const unsigned char* bp = (const unsigned char*)maskRaw + b * N_ + tid * 8;
#pragma unroll
    for (int e = 0; e < 8; e++) bits |= (unsigned)(bp[e] != 0) << e;
  }
  const int myc = __popc(bits);
  int pre = myc;
#pragma unroll
  for (int s = 1; s < 64; s <<= 1) {
    const int t = __shfl_up(pre, s);
    if ((tid & 63) >= s) pre += t;
  }
  const int w = tid >> 6;
  if ((tid & 63) == 63) warpOff[w] = pre;
  __syncthreads();
  int wbase = 0;
#pragma unroll
  for (int ww = 0; ww < 4; ww++) wbase += (ww < w) ? warpOff[ww] : 0;
  int pos = wbase + pre - myc;  // exclusive prefix
  const int m = warpOff[0] + warpOff[1] + warpOff[2] + warpOff[3];

  const int* gp = groups + b * N_;
#pragma unroll
  for (int e = 0; e < 8; e++) {
    if (bits & (1u << e)) {
      const int i = tid * 8 + e;
      idx[b * N_ + pos] = i;
      gc[b * N_ + pos] = gp[i];
      pos++;
    }
  }
  if (tid == 0) mcnt[b] = m;
  const int mpad = (m + 63) & ~63;
  if (tid < 64 && m + tid < mpad) gc[b * N_ + m + tid] = 0x10000;  // pad sentinel
  if (b == 0 && tid == 0) { gsum[0] = 0.f; gsum[1] = 0.f; *done = 0; }
}

// One wave per compacted row: gather emb[idx[k]], L2-normalize, bf16 -> zc.
// XCD-swizzled so zc[b] is written (and cached) on XCD b.
__global__ void gather_kernel(const float* __restrict__ emb, const int* __restrict__ idx,
                              const int* __restrict__ mcnt, unsigned short* __restrict__ zc) {
  const unsigned lin = blockIdx.x;
  const int b = lin & 7;
  const int rr = lin >> 3;  // 0..511
  const int w = threadIdx.x >> 6, l = threadIdx.x & 63;
  const int k = rr * 4 + w;
  const int m = mcnt[b];
  const int mpad = (m + 63) & ~63;
  if (k >= mpad) return;
  ushort4 o = {0, 0, 0, 0};
  if (k < m) {
    const int i = idx[b * N_ + k];
    const float4 v = *(const float4*)(emb + ((size_t)b * N_ + i) * D_ + l * 4);
    float ss = v.x * v.x + v.y * v.y + v.z * v.z + v.w * v.w;
#pragma unroll
    for (int s = 1; s < 64; s <<= 1) ss += __shfl_xor(ss, s);
    const float inv = 1.f / fmaxf(sqrtf(ss), 1e-12f);
    union { ushort4 u; __hip_bfloat162 h[2]; } p;
    p.h[0] = __float22bfloat162_rn(float2{v.x * inv, v.y * inv});
    p.h[1] = __float22bfloat162_rn(float2{v.z * inv, v.w * inv});
    o = p.u;
  }
  *(ushort4*)(zc + ((size_t)b * N_ + k) * D_ + l * 4) = o;
}

// Issue the 8 bfrag b128 loads + gj for (tile ctv, sub subv).
#define LOADB(dst, gjdst, ctv, subv)                                      \
  {                                                                       \
    const int _j = (ctv) * 64 + (subv) * 16 + l15;                        \
    const unsigned short* _bp = zb + (size_t)_j * D_ + lg * 8;            \
    _Pragma("unroll")                                                     \
    for (int _kt = 0; _kt < 8; _kt++)                                     \
      dst[_kt] = *(const bf16x8*)(_bp + _kt * 32);                        \
    gjdst = gb[_j];                                                       \
  }

#define STEP(bcur, gjcur, ctv, subv, diagv)                               \
  {                                                                       \
    f32x4 acc = {0.f, 0.f, 0.f, 0.f};                                     \
    _Pragma("unroll")                                                     \
    for (int _kt = 0; _kt < 8; _kt++)                                     \
      acc = __builtin_amdgcn_mfma_f32_16x16x32_bf16(afrag[_kt], bcur[_kt], \
                                                    acc, 0, 0, 0);        \
    const int _j = (ctv) * 64 + (subv) * 16 + l15;                        \
    const float _bias = (gjcur & 0x10000) ? NEGB : 0.f;                   \
    _Pragma("unroll")                                                     \
    for (int _r = 0; _r < 4; _r++) {                                      \
      float _a = _bias;                                                   \
      if ((diagv) && _j == irow[_r]) _a = NEGB;                           \
      const float _e = __builtin_exp2f(fmaf(acc[_r], 14.4269504089f, _a)); \
      dP[_r] += _e;                                                       \
      if (gjcur == gi[_r]) nP[_r] += _e;                                  \
    }                                                                     \
  }

// 1D grid, b = lin&7 (XCD-local). 4 waves x 16 rows per block; column tiles
// ct = y, y+NCH, ... B-fragments direct from global (L2-hot), 2-deep A/B
// ping-pong. sched_barrier(0) between every LOADB and STEP pins the issue
// order so hipcc cannot sink prefetch loads into their consuming STEP
// (r6: VGPR=48 proved it JIT-serialized every load at full latency).
__global__ __launch_bounds__(256, 3) void main_kernel(
    const unsigned short* __restrict__ zc, const int* __restrict__ gc,
    const int* __restrict__ mcnt, float* __restrict__ pd, float* __restrict__ pn) {
  const unsigned lin = blockIdx.x;
  const int b = lin & 7;
  const int rr = lin >> 3;     // 0..127
  const int x = rr & 31;       // row-block
  const int y = rr >> 5;       // chunk 0..3
  const int m = mcnt[b];
  const int rowBase = x * BROWS;
  if (rowBase >= m) return;
  const int ntiles = (m + 63) >> 6;
  const int nt = (ntiles - y + NCH - 1) / NCH;
  if (nt <= 0) return;

  const int tid = threadIdx.x;
  const int w = tid >> 6, l = tid & 63, l15 = l & 15, lg = l >> 4;
  const unsigned short* zb = zc + (size_t)b * N_ * D_;
  const int* gb = gc + b * N_;

  // A fragment: lane holds row (l&15), k = kt*32 + lg*8 + e
  bf16x8 afrag[8];
  const int arow = rowBase + w * 16 + l15;
#pragma unroll
  for (int kt = 0; kt < 8; kt++)
    afrag[kt] = *(const bf16x8*)(zb + (size_t)arow * D_ + kt * 32 + lg * 8);

  int irow[4], gi[4];
#pragma unroll
  for (int r = 0; r < 4; r++) {
    irow[r] = rowBase + w * 16 + lg * 4 + r;  // C/D row map
    gi[r] = gb[irow[r]];
  }

  float dP[4] = {0.f, 0.f, 0.f, 0.f};
  float nP[4] = {0.f, 0.f, 0.f, 0.f};

  bf16x8 bA[8], bB[8];
  int gjA, gjB;
  LOADB(bA, gjA, y, 0);  // prologue: (tile y, sub 0)
  SB();

  for (int it = 0; it < nt; it++) {
    const int ct = y + it * NCH;
    const int ctn = (it + 1 < nt) ? ct + NCH : ct;  // clamped (extra loads ok)
    const bool diagT = (ct == x);                   // block-uniform
    LOADB(bB, gjB, ct, 1);
    SB();
    STEP(bA, gjA, ct, 0, diagT);
    SB();
    LOADB(bA, gjA, ct, 2);
    SB();
    STEP(bB, gjB, ct, 1, diagT);
    SB();
    LOADB(bB, gjB, ct, 3);
    SB();
    STEP(bA, gjA, ct, 2, diagT);
    SB();
    LOADB(bA, gjA, ctn, 0);
    SB();
    STEP(bB, gjB, ct, 3, diagT);
    SB();
  }

  // reduce over the 16-lane column axis; lane l15==0 owns the row
#pragma unroll
  for (int r = 0; r < 4; r++) {
    float d = dP[r], n = nP[r];
#pragma unroll
    for (int mm = 1; mm < 16; mm <<= 1) {
      d += __shfl_xor(d, mm);
      n += __shfl_xor(n, mm);
    }
    if (l15 == 0) {
      const int row = rowBase + w * 16 + lg * 4 + r;
      const size_t o = ((size_t)y * B_ + b) * N_ + row;  // [chunk][b][row]
      pd[o] = d;
      pn[o] = n;
    }
  }
}

// Per compacted row: loss contribution; fused final division via done-counter.
__global__ void finalize_kernel(const float* __restrict__ pd, const float* __restrict__ pn,
                                const int* __restrict__ mcnt, float* gsum, int* done,
                                float* out) {
  const int g = blockIdx.x * 256 + threadIdx.x;
  const int b = g >> 11, k = g & (N_ - 1);
  const int m = mcnt[b];
  float contrib = 0.f, cnt = 0.f;
  if (k < m) {
    const int nch = min(NCH, (m + 63) >> 6);
    float d = 0.f, n = 0.f;
    for (int c = 0; c < nch; c++) {
      d += pd[((size_t)c * B_ + b) * N_ + k];
      n += pn[((size_t)c * B_ + b) * N_ + k];
    }
    if (n > 0.f) {
      contrib = __logf(d) - __logf(n);  // -log(numer/denom)
      cnt = 1.f;
    }
  }
#pragma unroll
  for (int s = 1; s < 64; s <<= 1) {
    contrib += __shfl_xor(contrib, s);
    cnt += __shfl_xor(cnt, s);
  }
  __shared__ float sc[4], sn[4];
  __shared__ bool isLast;
  const int w = threadIdx.x >> 6;
  if ((threadIdx.x & 63) == 0) { sc[w] = contrib; sn[w] = cnt; }
  __syncthreads();
  if (threadIdx.x == 0) {
    atomicAdd(&gsum[0], sc[0] + sc[1] + sc[2] + sc[3]);
    atomicAdd(&gsum[1], sn[0] + sn[1] + sn[2] + sn[3]);
    __threadfence();
    isLast = (atomicAdd(done, 1) == (int)gridDim.x - 1);
  }
  __syncthreads();
  if (isLast && threadIdx.x == 0) {
    const float s = atomicAdd(&gsum[0], 0.f);  // coherent read
    const float c = atomicAdd(&gsum[1], 0.f);
    out[0] = (c > 0.f) ? s / fmaxf(c, 1.f) : 0.f;
  }
}

extern "C" void kernel_launch(void* const* d_in, const int* in_sizes, int n_in,
                              void* d_out, int out_size, void* d_ws, size_t ws_size,
                              hipStream_t stream) {
  const float* emb = (const float*)d_in[0];
  const int* groups = (const int*)d_in[1];
  const void* mask = d_in[2];
  float* out = (float*)d_out;

  char* ws = (char*)d_ws;
  float* gsum = (float*)ws;
  int* done = (int*)(ws + 64);
  int* mcnt = (int*)(ws + 128);
  int* idx = (int*)(ws + 192);
  int* gc = (int*)(ws + 65728);
  unsigned short* zc = (unsigned short*)(ws + 131264);
  float* pd = (float*)(ws + 8519872);
  float* pn = (float*)(ws + 9044160);

  scan_kernel<<<B_, 256, 0, stream>>>(mask, groups, idx, gc, mcnt, gsum, done);
  gather_kernel<<<B_ * 512, 256, 0, stream>>>(emb, idx, mcnt, zc);
  main_kernel<<<B_ * 32 * NCH, 256, 0, stream>>>(zc, gc, mcnt, pd, pn);
  finalize_kernel<<<(B_ * N_) / 256, 256, 0, stream>>>(pd, pn, mcnt, gsum, done, out);
}

// Round 8
// 37.871 us; speedup vs baseline: 1.8778x; 1.8778x over previous
//
#include <hip/hip_runtime.h>
#include <hip/hip_bf16.h>

// InfoNCE loss, B=8, N=2048, D=256, T=0.1 — mask-compacted, XCD-local,
// r4-style global_load_lds double-buffered pipeline at 4 blocks/CU.
// ws layout (~9.6 MB):
//   [0]       float gsum[16] (0: loss sum, 1: count)
//   [64]      int   done
//   [128]     int   mcnt[B]
//   [192]     int   idx[B][2048]      compacted -> original index
//   [65728]   int   gc[B][2048]       compacted groups (pad = 0x10000)
//   [131264]  ushort zc[B][2048][256] compacted bf16-normalized rows
//   [8519872] float pd[NCH][B][2048]  per-chunk denom partials
//   [9044160] float pn[NCH][B][2048]  per-chunk numer partials

#define B_ 8
#define N_ 2048
#define D_ 256
#define NCH 8     // column-tile chunks (tile t -> chunk t%NCH)
#define BROWS 64  // rows per block = 4 waves x 16 rows
#define TCOLS 32  // columns per LDS tile (16 KB) -> dbuf 32.25 KB, 4 blocks/CU
#define NEGB -16384.0f

typedef __attribute__((ext_vector_type(8))) short bf16x8;
typedef __attribute__((ext_vector_type(4))) float f32x4;

__device__ __forceinline__ void gload16(const void* g, void* l) {
  __builtin_amdgcn_global_load_lds(
      (const __attribute__((address_space(1))) void*)g,
      (__attribute__((address_space(3))) void*)l, 16, 0, 0);
}

// One block per batch: detect mask dtype, prefix-scan mask, emit compacted
// index list + compacted groups (+sentinel pad), per-batch count. Block 0
// also zeroes the global accumulators.
__global__ void scan_kernel(const void* __restrict__ maskRaw, const int* __restrict__ groups,
                            int* __restrict__ idx, int* __restrict__ gc,
                            int* __restrict__ mcnt, float* gsum, int* done) {
  const int b = blockIdx.x, tid = threadIdx.x;
  __shared__ int cnt_s;
  __shared__ int warpOff[4];
  if (tid == 0) cnt_s = 0;
  __syncthreads();
  // dtype detect over first 16KB (in-bounds for both bool and int32)
  const int4* p4 = (const int4*)maskRaw;
  int c = 0;
  for (int i = tid; i < 1024; i += 256) {
    const int4 v = p4[i];
    c += ((v.x & 0xFFFFFF00) != 0) + ((v.y & 0xFFFFFF00) != 0) +
         ((v.z & 0xFFFFFF00) != 0) + ((v.w & 0xFFFFFF00) != 0);
  }
  atomicAdd(&cnt_s, c);
  __syncthreads();
  const bool isInt = (cnt_s == 0);  // int32 0/1 values: upper bytes all zero

  unsigned int bits = 0;
  if (isInt) {
    const int* ip = (const int*)maskRaw + b * N_ + tid * 8;
#pragma unroll
    for (int e = 0; e < 8; e++) bits |= (unsigned)(ip[e] != 0) << e;
  } else {
    const unsigned char* bp = (const unsigned char*)maskRaw + b * N_ + tid * 8;
#pragma unroll
    for (int e = 0; e < 8; e++) bits |= (unsigned)(bp[e] != 0) << e;
  }
  const int myc = __popc(bits);
  int pre = myc;
#pragma unroll
  for (int s = 1; s < 64; s <<= 1) {
    const int t = __shfl_up(pre, s);
    if ((tid & 63) >= s) pre += t;
  }
  const int w = tid >> 6;
  if ((tid & 63) == 63) warpOff[w] = pre;
  __syncthreads();
  int wbase = 0;
#pragma unroll
  for (int ww = 0; ww < 4; ww++) wbase += (ww < w) ? warpOff[ww] : 0;
  int pos = wbase + pre - myc;  // exclusive prefix
  const int m = warpOff[0] + warpOff[1] + warpOff[2] + warpOff[3];

  const int* gp = groups + b * N_;
#pragma unroll
  for (int e = 0; e < 8; e++) {
    if (bits & (1u << e)) {
      const int i = tid * 8 + e;
      idx[b * N_ + pos] = i;
      gc[b * N_ + pos] = gp[i];
      pos++;
    }
  }
  if (tid == 0) mcnt[b] = m;
  const int mpad = (m + 63) & ~63;
  if (tid < 64 && m + tid < mpad) gc[b * N_ + m + tid] = 0x10000;  // pad sentinel
  if (b == 0 && tid == 0) { gsum[0] = 0.f; gsum[1] = 0.f; *done = 0; }
}

// One wave per compacted row: gather emb[idx[k]], L2-normalize, bf16 -> zc.
// XCD-swizzled so zc[b] is written (and cached) on XCD b.
__global__ void gather_kernel(const float* __restrict__ emb, const int* __restrict__ idx,
                              const int* __restrict__ mcnt, unsigned short* __restrict__ zc) {
  const unsigned lin = blockIdx.x;
  const int b = lin & 7;
  const int rr = lin >> 3;  // 0..511
  const int w = threadIdx.x >> 6, l = threadIdx.x & 63;
  const int k = rr * 4 + w;
  const int m = mcnt[b];
  const int mpad = (m + 63) & ~63;
  if (k >= mpad) return;
  ushort4 o = {0, 0, 0, 0};
  if (k < m) {
    const int i = idx[b * N_ + k];
    const float4 v = *(const float4*)(emb + ((size_t)b * N_ + i) * D_ + l * 4);
    float ss = v.x * v.x + v.y * v.y + v.z * v.z + v.w * v.w;
#pragma unroll
    for (int s = 1; s < 64; s <<= 1) ss += __shfl_xor(ss, s);
    const float inv = 1.f / fmaxf(sqrtf(ss), 1e-12f);
    union { ushort4 u; __hip_bfloat162 h[2]; } p;
    p.h[0] = __float22bfloat162_rn(float2{v.x * inv, v.y * inv});
    p.h[1] = __float22bfloat162_rn(float2{v.z * inv, v.w * inv});
    o = p.u;
  }
  *(ushort4*)(zc + ((size_t)b * N_ + k) * D_ + l * 4) = o;
}

// 1D grid, b = lin&7 (XCD-local). 4 waves x 16 rows = 64 compacted rows per
// block; 32-col LDS tiles ct = y, y+NCH, ... staged via global_load_lds
// (no VGPR cost, no waitcnt fights) into a double buffer; one barrier per
// tile; prefetch issued before compute so the drain lands after the MFMAs.
// 4 blocks/CU so barrier/latency stalls overlap across independent blocks.
__global__ __launch_bounds__(256, 4) void main_kernel(
    const unsigned short* __restrict__ zc, const int* __restrict__ gc,
    const int* __restrict__ mcnt, float* __restrict__ pd, float* __restrict__ pn) {
  __shared__ unsigned short colZ[2][TCOLS * 256];  // 2 x 16 KB
  __shared__ int gjs[2][TCOLS];

  const unsigned lin = blockIdx.x;
  const int b = lin & 7;
  const int rr = lin >> 3;     // 0..255
  const int x = rr & 31;       // row-block
  const int y = rr >> 5;       // chunk 0..7
  const int m = mcnt[b];
  const int rowBase = x * BROWS;
  if (rowBase >= m) return;
  const int ntiles = (m + TCOLS - 1) / TCOLS;  // 32-col tiles
  const int nt = (ntiles - y + NCH - 1) / NCH;
  if (nt <= 0) return;

  const int tid = threadIdx.x;
  const int w = tid >> 6, l = tid & 63, l15 = l & 15, lg = l >> 4;
  const unsigned short* zb = zc + (size_t)b * N_ * D_;
  const int* gb = gc + b * N_;

  // per-lane pre-swizzled source offset (involution: LDS[L] = G[L ^ ((row&7)<<4)],
  // row = L>>9; (L>>9)&7 == (tid>>5)&7 for every 4096B chunk of a 16KB tile)
  const int srcOff = (tid * 16) ^ (((tid >> 5) & 7) << 4);
  const int ldsOff = tid * 16;

#define STAGE(buf, ctv)                                                     \
  {                                                                         \
    const char* _s = (const char*)zb + (size_t)(ctv) * (TCOLS * 512) + srcOff; \
    char* _l = (char*)colZ[buf] + ldsOff;                                   \
    _Pragma("unroll")                                                       \
    for (int _i = 0; _i < 4; _i++) gload16(_s + _i * 4096, _l + _i * 4096); \
    if (tid < TCOLS) gjs[buf][tid] = gb[(ctv) * TCOLS + tid];               \
  }

  // prologue: stage tile y into buffer 0
  STAGE(0, y);

  // A fragment: lane holds row (l&15), k = kt*32 + lg*8 + e
  bf16x8 afrag[8];
  const int arow = rowBase + w * 16 + l15;
#pragma unroll
  for (int kt = 0; kt < 8; kt++)
    afrag[kt] = *(const bf16x8*)(zb + (size_t)arow * D_ + kt * 32 + lg * 8);

  int irow[4], gi[4];
#pragma unroll
  for (int r = 0; r < 4; r++) {
    irow[r] = rowBase + w * 16 + lg * 4 + r;  // C/D row map
    gi[r] = gb[irow[r]];
  }

  float dP[4] = {0.f, 0.f, 0.f, 0.f};
  float nP[4] = {0.f, 0.f, 0.f, 0.f};

  __syncthreads();  // tile 0 ready (compiler folds vmcnt(0) into barrier)

  int cur = 0;
  for (int it = 0; it < nt; it++) {
    const int ct = y + it * NCH;
    if (it + 1 < nt) STAGE(cur ^ 1, ct + NCH);   // prefetch next tile
    const bool diagT = ((ct >> 1) == x);         // block-uniform diag test
    const char* bufc = (const char*)colZ[cur];
#pragma unroll
    for (int sub = 0; sub < 2; sub++) {
      f32x4 acc = {0.f, 0.f, 0.f, 0.f};
      const int brow = sub * 16 + l15;
      const char* bbase = bufc + brow * 512;
      const int bx = (brow & 7) << 4;
#pragma unroll
      for (int kt = 0; kt < 8; kt++) {
        const bf16x8 bfrag = *(const bf16x8*)(bbase + ((lg * 16 + kt * 64) ^ bx));
        acc = __builtin_amdgcn_mfma_f32_16x16x32_bf16(afrag[kt], bfrag, acc, 0, 0, 0);
      }
      const int j = ct * TCOLS + sub * 16 + l15;
      const int gj = gjs[cur][sub * 16 + l15];
      const float bias = (gj & 0x10000) ? NEGB : 0.f;  // pad col -> exp == 0
#pragma unroll
      for (int r = 0; r < 4; r++) {
        float a0 = bias;
        if (diagT && j == irow[r]) a0 = NEGB;  // exclude diagonal
        const float e0 = __builtin_exp2f(fmaf(acc[r], 14.4269504089f, a0));
        dP[r] += e0;
        if (gj == gi[r]) nP[r] += e0;
      }
    }
    __syncthreads();  // drains prefetch (after compute) + protects buffers
    cur ^= 1;
  }

  // reduce over the 16-lane column axis; lane l15==0 owns the row
#pragma unroll
  for (int r = 0; r < 4; r++) {
    float d = dP[r], n = nP[r];
#pragma unroll
    for (int mm = 1; mm < 16; mm <<= 1) {
      d += __shfl_xor(d, mm);
      n += __shfl_xor(n, mm);
    }
    if (l15 == 0) {
      const int row = rowBase + w * 16 + lg * 4 + r;
      const size_t o = ((size_t)y * B_ + b) * N_ + row;  // [chunk][b][row]
      pd[o] = d;
      pn[o] = n;
    }
  }
#undef STAGE
}

// Per compacted row: loss contribution; fused final division via done-counter.
__global__ void finalize_kernel(const float* __restrict__ pd, const float* __restrict__ pn,
                                const int* __restrict__ mcnt, float* gsum, int* done,
                                float* out) {
  const int g = blockIdx.x * 256 + threadIdx.x;
  const int b = g >> 11, k = g & (N_ - 1);
  const int m = mcnt[b];
  float contrib = 0.f, cnt = 0.f;
  if (k < m) {
    const int nch = min(NCH, (m + TCOLS - 1) / TCOLS);
    float d = 0.f, n = 0.f;
    for (int c = 0; c < nch; c++) {
      d += pd[((size_t)c * B_ + b) * N_ + k];
      n += pn[((size_t)c * B_ + b) * N_ + k];
    }
    if (n > 0.f) {
      contrib = __logf(d) - __logf(n);  // -log(numer/denom)
      cnt = 1.f;
    }
  }
#pragma unroll
  for (int s = 1; s < 64; s <<= 1) {
    contrib += __shfl_xor(contrib, s);
    cnt += __shfl_xor(cnt, s);
  }
  __shared__ float sc[4], sn[4];
  __shared__ bool isLast;
  const int w = threadIdx.x >> 6;
  if ((threadIdx.x & 63) == 0) { sc[w] = contrib; sn[w] = cnt; }
  __syncthreads();
  if (threadIdx.x == 0) {
    atomicAdd(&gsum[0], sc[0] + sc[1] + sc[2] + sc[3]);
    atomicAdd(&gsum[1], sn[0] + sn[1] + sn[2] + sn[3]);
    __threadfence();
    isLast = (atomicAdd(done, 1) == (int)gridDim.x - 1);
  }
  __syncthreads();
  if (isLast && threadIdx.x == 0) {
    const float s = atomicAdd(&gsum[0], 0.f);  // coherent read
    const float c = atomicAdd(&gsum[1], 0.f);
    out[0] = (c > 0.f) ? s / fmaxf(c, 1.f) : 0.f;
  }
}

extern "C" void kernel_launch(void* const* d_in, const int* in_sizes, int n_in,
                              void* d_out, int out_size, void* d_ws, size_t ws_size,
                              hipStream_t stream) {
  const float* emb = (const float*)d_in[0];
  const int* groups = (const int*)d_in[1];
  const void* mask = d_in[2];
  float* out = (float*)d_out;

  char* ws = (char*)d_ws;
  float* gsum = (float*)ws;
  int* done = (int*)(ws + 64);
  int* mcnt = (int*)(ws + 128);
  int* idx = (int*)(ws + 192);
  int* gc = (int*)(ws + 65728);
  unsigned short* zc = (unsigned short*)(ws + 131264);
  float* pd = (float*)(ws + 8519872);
  float* pn = (float*)(ws + 9044160);

  scan_kernel<<<B_, 256, 0, stream>>>(mask, groups, idx, gc, mcnt, gsum, done);
  gather_kernel<<<B_ * 512, 256, 0, stream>>>(emb, idx, mcnt, zc);
  main_kernel<<<B_ * 32 * NCH, 256, 0, stream>>>(zc, gc, mcnt, pd, pn);
  finalize_kernel<<<(B_ * N_) / 256, 256, 0, stream>>>(pd, pn, mcnt, gsum, done, out);
}